// Round 2
// baseline (8958.761 us; speedup 1.0000x reference)
//
#include <hip/hip_runtime.h>
#include <hip/hip_fp16.h>
#include <hip/hip_cooperative_groups.h>

namespace cg = cooperative_groups;

typedef _Float16 f16;
typedef _Float16 half8 __attribute__((ext_vector_type(8)));
typedef float f32x4 __attribute__((ext_vector_type(4)));

#define DIMD 1024
#define NB 64
#define NT 256
#define G4 4096
#define EMBD 256

__device__ __forceinline__ float sigm(float x) { return 1.f / (1.f + __expf(-x)); }
__device__ __forceinline__ float tanh_(float x) {
  float e = __expf(-2.f * fabsf(x));          // e in (0,1], no overflow
  float t = (1.f - e) / (1.f + e);
  return x >= 0.f ? t : -t;
}

// ---- async global->LDS, 16B per lane, linear dest ----
__device__ __forceinline__ void gload_lds16(const void* g, void* l) {
  __builtin_amdgcn_global_load_lds(
      (const __attribute__((address_space(1))) void*)g,
      (__attribute__((address_space(3))) void*)l, 16, 0, 0);
}

// =====================================================================
// BT-GEMM: C[M,N] = A[M,K] * B[N,K]^T + bias[N].  M fixed via grid.x*128.
// 128x128 tile, BK=64, 4 waves (each 64x64), fp16 in, fp32 acc.
// XOR chunk swizzle (16B chunks within 128B row) applied to the staging
// SOURCE address and to the ds_read address (same involution) -> <=2-way.
// =====================================================================
template<int OUTF32>
__global__ __launch_bounds__(256)
void gemm_bt(const f16* __restrict__ A, const f16* __restrict__ Bm,
             void* __restrict__ Cout, const float* __restrict__ bias,
             int N, int K)
{
  __shared__ __align__(16) f16 As[128 * 64];
  __shared__ __align__(16) f16 Bs[128 * 64];
  const int tid = threadIdx.x;
  const int w = tid >> 6, l = tid & 63;
  const int li = l & 15, lg = l >> 4;
  const int tm = blockIdx.x * 128, tn = blockIdx.y * 128;
  const int wm = (w >> 1) * 64, wn = (w & 1) * 64;

  f32x4 acc[4][4] = {};

  for (int kt = 0; kt < K; kt += 64) {
#pragma unroll
    for (int i = 0; i < 4; ++i) {           // stage A tile (linear LDS dest)
      int r = i * 32 + w * 8 + (l >> 3);
      int c = (l & 7) ^ (r & 7);
      gload_lds16(A + (size_t)(tm + r) * K + kt + c * 8, As + (i * 32 + w * 8) * 64);
    }
#pragma unroll
    for (int i = 0; i < 4; ++i) {           // stage B tile
      int r = i * 32 + w * 8 + (l >> 3);
      int c = (l & 7) ^ (r & 7);
      gload_lds16(Bm + (size_t)(tn + r) * K + kt + c * 8, Bs + (i * 32 + w * 8) * 64);
    }
    __syncthreads();
#pragma unroll
    for (int kk = 0; kk < 2; ++kk) {
      half8 a[4], b[4];
#pragma unroll
      for (int mi = 0; mi < 4; ++mi) {
        int row = wm + mi * 16 + li;
        int ch = (kk * 4 + lg) ^ (row & 7);
        a[mi] = *(const half8*)(As + row * 64 + ch * 8);
      }
#pragma unroll
      for (int ni = 0; ni < 4; ++ni) {
        int row = wn + ni * 16 + li;
        int ch = (kk * 4 + lg) ^ (row & 7);
        b[ni] = *(const half8*)(Bs + row * 64 + ch * 8);
      }
#pragma unroll
      for (int mi = 0; mi < 4; ++mi)
#pragma unroll
        for (int ni = 0; ni < 4; ++ni)
          acc[mi][ni] = __builtin_amdgcn_mfma_f32_16x16x32_f16(a[mi], b[ni], acc[mi][ni], 0, 0, 0);
    }
    __syncthreads();
  }

#pragma unroll
  for (int mi = 0; mi < 4; ++mi)
#pragma unroll
    for (int ni = 0; ni < 4; ++ni) {
      int row0 = tm + wm + mi * 16 + lg * 4;   // D row = lg*4+r, col = li
      int col = tn + wn + ni * 16 + li;
      float bv = bias[col];
      if (OUTF32) {
        float* C = (float*)Cout;
#pragma unroll
        for (int r = 0; r < 4; ++r)
          C[(size_t)(row0 + r) * N + col] = acc[mi][ni][r] + bv;
      } else {
        f16* C = (f16*)Cout;
#pragma unroll
        for (int r = 0; r < 4; ++r)
          C[(size_t)(row0 + r) * N + col] = (f16)(acc[mi][ni][r] + bv);
      }
    }
}

// =====================================================================
// Fused 2-layer persistent LSTM recurrence. 128 blocks x 256 threads.
// Block g owns hidden slice d0=g*8 for BOTH layers (32 gate rows each).
// Software pipeline: interval k computes layer0 step k (uses a[k-1]) and
// layer1 step k-1 (uses z[k-2] and a[k-1]). ONE grid.sync per interval.
// Three weight slices (Whh0, Whh1, Wih1; 32 rows x 1024 each) live in
// REGISTERS, wave w owning K quarter [w*256,(w+1)*256). Gate partials
// K-reduced through padded LDS. c-states in registers. a/z ping-pong in
// global f16; layer1's input GEMM folded in (no xg1 buffer at all).
// =====================================================================
__global__ __launch_bounds__(256, 1)
void lstm_fused(const f16* __restrict__ xg0, const f16* __restrict__ Whh0,
                const f16* __restrict__ Whh1, const f16* __restrict__ Wih1,
                const float* __restrict__ bsum1,
                const float* __restrict__ h0, const float* __restrict__ c0,
                f16* __restrict__ h2seq, f16* __restrict__ aping,
                f16* __restrict__ zping, float* __restrict__ hT,
                float* __restrict__ cT)
{
  const int d0 = blockIdx.x * 8;
  const int tid = threadIdx.x;
  const int w = tid >> 6, l = tid & 63;
  const int li = l & 15, lg = l >> 4;

  __shared__ __align__(16) float part[4][64][40];   // pad 40: 2-way banks only

  // ---- three register-resident weight slices (A-operand fragments)
  half8 wf0[2][8], wfZ[2][8], wfI[2][8];
#pragma unroll
  for (int mt = 0; mt < 2; ++mt) {
    int rr = mt * 16 + li;                          // rr = q*8 + j
    size_t grow = (size_t)((rr >> 3) * DIMD + d0 + (rr & 7)) * DIMD;
#pragma unroll
    for (int kk = 0; kk < 8; ++kk) {
      int kidx = w * 256 + kk * 32 + lg * 8;
      wf0[mt][kk] = *(const half8*)(Whh0 + grow + kidx);
      wfZ[mt][kk] = *(const half8*)(Whh1 + grow + kidx);
      wfI[mt][kk] = *(const half8*)(Wih1 + grow + kidx);
    }
  }

  const int jj = tid & 7;                           // same j for both i slots
  float bs1[4];
#pragma unroll
  for (int q = 0; q < 4; ++q) bs1[q] = bsum1[q * DIMD + d0 + jj];

  // ---- init states; a[-1] -> aping slot1, z[-1] -> zping slot1
  float c0reg[2], c1reg[2];
  f16 xpre[2][4];
#pragma unroll
  for (int i = 0; i < 2; ++i) {
    int p = tid + i * 256;
    int b = p >> 3, j = p & 7;
    int off = b * DIMD + d0 + j;
    c0reg[i] = c0[off];
    c1reg[i] = c0[NB * DIMD + off];
    aping[NB * DIMD + off] = (f16)h0[off];
    zping[NB * DIMD + off] = (f16)h0[NB * DIMD + off];
#pragma unroll
    for (int q = 0; q < 4; ++q)                      // prefetch xg0 for step 0
      xpre[i][q] = xg0[(size_t)(b * NT) * G4 + q * DIMD + d0 + j];
  }

  cg::grid_group grid = cg::this_grid();

  for (int k = 0; k <= NT; ++k) {
    grid.sync();                                     // a[k-1], z[k-2] visible
    const bool do0 = (k < NT);                       // layer0 step k
    const bool do1 = (k >= 1);                       // layer1 step k-1
    const f16* aprev = aping + ((k + 1) & 1) * (NB * DIMD);
    f16*       acur  = aping + (k & 1) * (NB * DIMD);
    const f16* zprev = zping + (k & 1) * (NB * DIMD);
    f16*       zcur  = zping + ((k + 1) & 1) * (NB * DIMD);

    f32x4 acc0[2][4] = {}, acc1[2][4] = {};
#pragma unroll 4
    for (int kk = 0; kk < 8; ++kk) {
      int kidx = w * 256 + kk * 32 + lg * 8;
      half8 hfA[4], hfZ[4];
#pragma unroll
      for (int nb = 0; nb < 4; ++nb) {
        int b = nb * 16 + li;
        hfA[nb] = *(const half8*)(aprev + (size_t)b * DIMD + kidx);
      }
      if (do1) {
#pragma unroll
        for (int nb = 0; nb < 4; ++nb) {
          int b = nb * 16 + li;
          hfZ[nb] = *(const half8*)(zprev + (size_t)b * DIMD + kidx);
        }
#pragma unroll
        for (int mt = 0; mt < 2; ++mt)
#pragma unroll
          for (int nb = 0; nb < 4; ++nb) {
            acc1[mt][nb] = __builtin_amdgcn_mfma_f32_16x16x32_f16(wfZ[mt][kk], hfZ[nb], acc1[mt][nb], 0, 0, 0);
            acc1[mt][nb] = __builtin_amdgcn_mfma_f32_16x16x32_f16(wfI[mt][kk], hfA[nb], acc1[mt][nb], 0, 0, 0);
          }
      }
      if (do0) {
#pragma unroll
        for (int mt = 0; mt < 2; ++mt)
#pragma unroll
          for (int nb = 0; nb < 4; ++nb)
            acc0[mt][nb] = __builtin_amdgcn_mfma_f32_16x16x32_f16(wf0[mt][kk], hfA[nb], acc0[mt][nb], 0, 0, 0);
      }
    }

    if (do0) {                                       // -------- layer0 step k
#pragma unroll
      for (int mt = 0; mt < 2; ++mt)
#pragma unroll
        for (int nb = 0; nb < 4; ++nb)
          *(f32x4*)&part[w][nb * 16 + li][mt * 16 + lg * 4] = acc0[mt][nb];
      __syncthreads();
#pragma unroll
      for (int i = 0; i < 2; ++i) {
        int p = tid + i * 256;
        int b = p >> 3, j = p & 7;
        int off = b * DIMD + d0 + j;
        float gi = part[0][b][j]      + part[1][b][j]      + part[2][b][j]      + part[3][b][j]      + (float)xpre[i][0];
        float gf = part[0][b][8 + j]  + part[1][b][8 + j]  + part[2][b][8 + j]  + part[3][b][8 + j]  + (float)xpre[i][1];
        float gg = part[0][b][16 + j] + part[1][b][16 + j] + part[2][b][16 + j] + part[3][b][16 + j] + (float)xpre[i][2];
        float go = part[0][b][24 + j] + part[1][b][24 + j] + part[2][b][24 + j] + part[3][b][24 + j] + (float)xpre[i][3];
        float cn = sigm(gf) * c0reg[i] + sigm(gi) * tanh_(gg);
        float hn = sigm(go) * tanh_(cn);
        c0reg[i] = cn;
        acur[off] = (f16)hn;
        if (k == NT - 1) { hT[off] = hn; cT[off] = cn; }
      }
      __syncthreads();                               // part reads done
    }

    if (do1) {                                       // -------- layer1 step k-1
#pragma unroll
      for (int mt = 0; mt < 2; ++mt)
#pragma unroll
        for (int nb = 0; nb < 4; ++nb)
          *(f32x4*)&part[w][nb * 16 + li][mt * 16 + lg * 4] = acc1[mt][nb];
      __syncthreads();
#pragma unroll
      for (int i = 0; i < 2; ++i) {
        int p = tid + i * 256;
        int b = p >> 3, j = p & 7;
        int off = b * DIMD + d0 + j;
        float gi = part[0][b][j]      + part[1][b][j]      + part[2][b][j]      + part[3][b][j]      + bs1[0];
        float gf = part[0][b][8 + j]  + part[1][b][8 + j]  + part[2][b][8 + j]  + part[3][b][8 + j]  + bs1[1];
        float gg = part[0][b][16 + j] + part[1][b][16 + j] + part[2][b][16 + j] + part[3][b][16 + j] + bs1[2];
        float go = part[0][b][24 + j] + part[1][b][24 + j] + part[2][b][24 + j] + part[3][b][24 + j] + bs1[3];
        float cn = sigm(gf) * c1reg[i] + sigm(gi) * tanh_(gg);
        float hn = sigm(go) * tanh_(cn);
        c1reg[i] = cn;
        zcur[off] = (f16)hn;
        h2seq[(size_t)(b * NT + (k - 1)) * DIMD + d0 + j] = (f16)hn;
        if (k == NT) { hT[NB * DIMD + off] = hn; cT[NB * DIMD + off] = cn; }
      }
      // no trailing barrier: next interval's part writes are after grid.sync
    }

    if (k + 1 < NT) {                                // prefetch xg0 for k+1
#pragma unroll
      for (int i = 0; i < 2; ++i) {
        int p = tid + i * 256;
        int b = p >> 3, j = p & 7;
#pragma unroll
        for (int q = 0; q < 4; ++q)
          xpre[i][q] = xg0[(size_t)(b * NT + (k + 1)) * G4 + q * DIMD + d0 + j];
      }
    }
  }
}

// =====================================================================
// Prep kernels
// =====================================================================
__global__ void wn_conv(const float* __restrict__ v, const float* __restrict__ gw,
                        f16* __restrict__ out, int K)
{
  int w = threadIdx.x >> 6, l = threadIdx.x & 63;
  int row = blockIdx.x * 4 + w;
  const float* vr = v + (size_t)row * K;
  float s = 0.f;
  for (int k = l; k < K; k += 64) { float x = vr[k]; s += x * x; }
#pragma unroll
  for (int off = 32; off > 0; off >>= 1) s += __shfl_xor(s, off, 64);
  float scale = gw[row] / sqrtf(s);
  f16* orow = out + (size_t)row * K;
  for (int k = l; k < K; k += 64) orow[k] = (f16)(vr[k] * scale);
}

__global__ void conv_f16(const float* __restrict__ src, f16* __restrict__ dst, int n4)
{
  int i = blockIdx.x * blockDim.x + threadIdx.x;
  if (i < n4) {
    float4 v = *(const float4*)(src + (size_t)i * 4);
    f16* d = dst + (size_t)i * 4;
    d[0] = (f16)v.x; d[1] = (f16)v.y; d[2] = (f16)v.z; d[3] = (f16)v.w;
  }
}

__global__ void bias_prep(const float* a0, const float* b0, const float* a1, const float* b1,
                          float* s0, float* s1)
{
  int i = blockIdx.x * blockDim.x + threadIdx.x;
  if (i < G4) { s0[i] = a0[i] + b0[i]; s1[i] = a1[i] + b1[i]; }
}

__global__ void embed_k(const int* __restrict__ x, const float* __restrict__ emb,
                        f16* __restrict__ e)
{
  int m = blockIdx.x;
  int k = threadIdx.x;
  e[(size_t)m * EMBD + k] = (f16)emb[(size_t)x[m] * EMBD + k];
}

// =====================================================================
extern "C" void kernel_launch(void* const* d_in, const int* in_sizes, int n_in,
                              void* d_out, int out_size, void* d_ws, size_t ws_size,
                              hipStream_t stream)
{
  (void)in_sizes; (void)n_in; (void)out_size; (void)ws_size;
  const int*   x     = (const int*)  d_in[0];
  const float* h0    = (const float*)d_in[1];
  const float* c0    = (const float*)d_in[2];
  const float* emb   = (const float*)d_in[3];
  const float* v_ih0 = (const float*)d_in[4];
  const float* g_ih0 = (const float*)d_in[5];
  const float* v_hh0 = (const float*)d_in[6];
  const float* g_hh0 = (const float*)d_in[7];
  const float* b_ih0 = (const float*)d_in[8];
  const float* b_hh0 = (const float*)d_in[9];
  const float* W_ih1 = (const float*)d_in[10];
  const float* W_hh1 = (const float*)d_in[11];
  const float* b_ih1 = (const float*)d_in[12];
  const float* b_hh1 = (const float*)d_in[13];
  const float* W_out = (const float*)d_in[14];
  const float* b_out = (const float*)d_in[15];

  char* ws = (char*)d_ws;
  size_t off = 0;
  auto alloc = [&](size_t bytes) { void* p = ws + off; off += (bytes + 255) & ~(size_t)255; return p; };
  f16*   Wih0h = (f16*)alloc((size_t)4096 * 256 * 2);
  f16*   Whh0h = (f16*)alloc((size_t)4096 * 1024 * 2);
  f16*   Wih1h = (f16*)alloc((size_t)4096 * 1024 * 2);
  f16*   Whh1h = (f16*)alloc((size_t)4096 * 1024 * 2);
  f16*   Wouth = (f16*)alloc((size_t)256 * 1024 * 2);
  float* bsum0 = (float*)alloc(4096 * 4);
  float* bsum1 = (float*)alloc(4096 * 4);
  f16*   e_h   = (f16*)alloc((size_t)16384 * 256 * 2);
  f16*   xg0   = (f16*)alloc((size_t)16384 * 4096 * 2);   // layer0 input gates
  f16*   h2s   = (f16*)alloc((size_t)16384 * 1024 * 2);   // layer1 output sequence
  f16*   aping = (f16*)alloc((size_t)2 * 64 * 1024 * 2);
  f16*   zping = (f16*)alloc((size_t)2 * 64 * 1024 * 2);
  // total ~196 MB

  float* logits = (float*)d_out;
  float* newh = logits + (size_t)16384 * 256;
  float* newc = newh + 2 * 64 * 1024;

  wn_conv<<<1024, 256, 0, stream>>>(v_ih0, g_ih0, Wih0h, 256);
  wn_conv<<<1024, 256, 0, stream>>>(v_hh0, g_hh0, Whh0h, 1024);
  conv_f16<<<4096, 256, 0, stream>>>(W_ih1, Wih1h, 1048576);
  conv_f16<<<4096, 256, 0, stream>>>(W_hh1, Whh1h, 1048576);
  conv_f16<<<256, 256, 0, stream>>>(W_out, Wouth, 65536);
  bias_prep<<<16, 256, 0, stream>>>(b_ih0, b_hh0, b_ih1, b_hh1, bsum0, bsum1);
  embed_k<<<16384, 256, 0, stream>>>(x, emb, e_h);

  // xg0 = e * W_ih0^T + (b_ih0 + b_hh0)
  gemm_bt<0><<<dim3(128, 32), 256, 0, stream>>>(e_h, Wih0h, xg0, bsum0, 4096, 256);

  { // fused 2-layer recurrence (layer1 lags layer0 by one step)
    const f16* xg_c = xg0; const f16* W0 = Whh0h; const f16* W1 = Whh1h; const f16* WI = Wih1h;
    const float* bs = bsum1; const float* h0p = h0; const float* c0p = c0;
    f16* hs = h2s; f16* ap = aping; f16* zp = zping;
    float* hTp = newh; float* cTp = newc;
    void* args[] = {&xg_c, &W0, &W1, &WI, &bs, &h0p, &c0p, &hs, &ap, &zp, &hTp, &cTp};
    hipLaunchCooperativeKernel((const void*)lstm_fused, dim3(128), dim3(256), args, 0, stream);
  }

  // logits = h2s * W_out^T + b_out  (fp32 out)
  gemm_bt<1><<<dim3(128, 2), 256, 0, stream>>>(h2s, Wouth, logits, b_out, 256, 1024);
}

// Round 10
// 6722.196 us; speedup vs baseline: 1.3327x; 1.3327x over previous
//
#include <hip/hip_runtime.h>
#include <hip/hip_fp16.h>

typedef _Float16 f16;
typedef _Float16 half8 __attribute__((ext_vector_type(8)));
typedef float f32x4 __attribute__((ext_vector_type(4)));

#define DIMD 1024
#define NB 64
#define NT 256
#define G4 4096
#define EMBD 256
#define MTOT 16384
#define NBLK 256
#define HSZ (NB * DIMD)
#define XGSTEP (NBLK * 1024)   // 262144 f16 per t-step in packed xg

__device__ __forceinline__ float sigm(float x) { return 1.f / (1.f + __expf(-x)); }
__device__ __forceinline__ float tanh_(float x) {
  float e = __expf(-2.f * fabsf(x));
  float t = (1.f - e) / (1.f + e);
  return x >= 0.f ? t : -t;
}

__device__ __forceinline__ void gload_lds16(const void* g, void* l) {
  __builtin_amdgcn_global_load_lds(
      (const __attribute__((address_space(1))) void*)g,
      (__attribute__((address_space(3))) void*)l, 16, 0, 0);
}

// =====================================================================
// BT-GEMM: A[M,K] * B[N,K]^T + bias. 128x128 tile, BK=64, 4 waves.
// MODE 2: out f16 PACKED xgP[t][bid][q][j][b]  (for lstm_fused)
// MODE 3: out f32, row-remap m2=t*64+b -> mout=b*NT+t, C[mout][N] (+bias)
// =====================================================================
template<int MODE>
__global__ __launch_bounds__(256)
void gemm_bt(const f16* __restrict__ A, const f16* __restrict__ Bm,
             void* __restrict__ Cout, const float* __restrict__ bias,
             int N, int K)
{
  __shared__ __align__(16) f16 As[128 * 64];
  __shared__ __align__(16) f16 Bs[128 * 64];
  const int tid = threadIdx.x;
  const int w = tid >> 6, l = tid & 63;
  const int li = l & 15, lg = l >> 4;
  const int tm = blockIdx.x * 128, tn = blockIdx.y * 128;
  const int wm = (w >> 1) * 64, wn = (w & 1) * 64;

  f32x4 acc[4][4] = {};

  for (int kt = 0; kt < K; kt += 64) {
#pragma unroll
    for (int i = 0; i < 4; ++i) {
      int r = i * 32 + w * 8 + (l >> 3);
      int c = (l & 7) ^ (r & 7);
      gload_lds16(A + (size_t)(tm + r) * K + kt + c * 8, As + (i * 32 + w * 8) * 64);
    }
#pragma unroll
    for (int i = 0; i < 4; ++i) {
      int r = i * 32 + w * 8 + (l >> 3);
      int c = (l & 7) ^ (r & 7);
      gload_lds16(Bm + (size_t)(tn + r) * K + kt + c * 8, Bs + (i * 32 + w * 8) * 64);
    }
    __syncthreads();
#pragma unroll
    for (int kk = 0; kk < 2; ++kk) {
      half8 a[4], b[4];
#pragma unroll
      for (int mi = 0; mi < 4; ++mi) {
        int row = wm + mi * 16 + li;
        int ch = (kk * 4 + lg) ^ (row & 7);
        a[mi] = *(const half8*)(As + row * 64 + ch * 8);
      }
#pragma unroll
      for (int ni = 0; ni < 4; ++ni) {
        int row = wn + ni * 16 + li;
        int ch = (kk * 4 + lg) ^ (row & 7);
        b[ni] = *(const half8*)(Bs + row * 64 + ch * 8);
      }
#pragma unroll
      for (int mi = 0; mi < 4; ++mi)
#pragma unroll
        for (int ni = 0; ni < 4; ++ni) {
          if (MODE == 2)  // D rows = gate(n-tile), cols = m
            acc[mi][ni] = __builtin_amdgcn_mfma_f32_16x16x32_f16(b[ni], a[mi], acc[mi][ni], 0, 0, 0);
          else            // D rows = m, cols = n
            acc[mi][ni] = __builtin_amdgcn_mfma_f32_16x16x32_f16(a[mi], b[ni], acc[mi][ni], 0, 0, 0);
        }
    }
    __syncthreads();
  }

#pragma unroll
  for (int mi = 0; mi < 4; ++mi)
#pragma unroll
    for (int ni = 0; ni < 4; ++ni) {
      if (MODE == 2) {
        // packed scatter: m = b*256+t (A rows), g4 = gate row (B rows)
        f16* C = (f16*)Cout;
        int m = tm + wm + mi * 16 + li;
        int t = m & 255, bb = m >> 8;
#pragma unroll
        for (int r = 0; r < 4; ++r) {
          int g4 = tn + wn + ni * 16 + lg * 4 + r;
          int q = g4 >> 10, dd = g4 & 1023;
          size_t adr = (size_t)t * XGSTEP + (size_t)(dd >> 2) * 1024 + q * 256 + (dd & 3) * 64 + bb;
          C[adr] = (f16)(acc[mi][ni][r] + bias[g4]);
        }
      } else {
        float* C = (float*)Cout;
        int col = tn + wn + ni * 16 + li;
        float bv = bias[col];
#pragma unroll
        for (int r = 0; r < 4; ++r) {
          int m2 = tm + wm + mi * 16 + lg * 4 + r;   // t-major: t*64+b
          int mout = (m2 & 63) * NT + (m2 >> 6);     // -> b*NT+t
          C[(size_t)mout * N + col] = acc[mi][ni][r] + bv;
        }
      }
    }
}

// =====================================================================
// Fused 2-layer persistent LSTM. 256 blocks x 256 threads, 1 block/CU
// (LDS 86KB). Block owns 4 d-columns (16 gate rows) per layer; weights
// register-resident (asm-pinned, inv-immune). Interval k: layer0 step k
// (reads a[k-1]) + layer1 step k-1 (reads z[k-2], a[k-1]).
// Two-level device barrier (16x16) with release->acquire; per-interval
// __threadfence() (agent-scope fence: waitcnt + cache inv) makes the
// ping-pong slot reuse safe (same-parity slot last read 2 intervals ago
// -> stale clean lines otherwise). xg read is a contiguous 2KB/block
// chunk per interval (packed layout), prefetched 1 interval ahead into
// registers (inv-immune).
// =====================================================================
__global__ __launch_bounds__(256, 1)
void lstm_fused(const f16* __restrict__ xgP, const f16* __restrict__ Whh0,
                const f16* __restrict__ Whh1, const f16* __restrict__ Wih1,
                const float* __restrict__ bsum1,
                const float* __restrict__ h0, const float* __restrict__ c0,
                f16* __restrict__ h2seq,      // [NT][64][1024] t-major
                f16* __restrict__ aping,      // [2][64][1024]
                f16* __restrict__ zinit,      // [64][1024]
                float* __restrict__ hT, float* __restrict__ cT,
                unsigned* __restrict__ ctr)   // 16 grp lines (x32) + root @1024
{
  const int bid = blockIdx.x;
  const int d0 = bid * 4;
  const int tid = threadIdx.x;
  const int w = tid >> 6, l = tid & 63;
  const int li = l & 15, lg = l >> 4;
  const int gid = bid >> 4;
  const bool leader = (bid & 15) == 0;

  __shared__ __align__(16) float part[4][64][84];   // 86016 B -> 1 block/CU

  // ---- weight fragments: 16 gate rows (q=li>>2, j=li&3), K quarter per wave
  half8 wf0[8], wfZ[8], wfI[8];
  {
    size_t grow = (size_t)((li >> 2) * DIMD + d0 + (li & 3)) * DIMD;
#pragma unroll
    for (int kk = 0; kk < 8; ++kk) {
      int kidx = w * 256 + kk * 32 + lg * 8;
      wf0[kk] = *(const half8*)(Whh0 + grow + kidx);
      wfZ[kk] = *(const half8*)(Whh1 + grow + kidx);
      wfI[kk] = *(const half8*)(Wih1 + grow + kidx);
    }
#pragma unroll
    for (int kk = 0; kk < 8; ++kk)
      asm volatile("" : "+v"(wf0[kk]), "+v"(wfZ[kk]), "+v"(wfI[kk]));
  }

  const int b = tid >> 2, j = tid & 3;
  const int off = b * DIMD + d0 + j;
  float bs1[4];
#pragma unroll
  for (int q = 0; q < 4; ++q) bs1[q] = bsum1[q * DIMD + d0 + j];

  // ---- init: c regs; a[-1] -> aping slot 1; z[-1] -> zinit; xg prefetch k=0
  float c0reg = c0[off];
  float c1reg = c0[HSZ + off];
  aping[HSZ + off] = (f16)h0[off];
  zinit[off] = (f16)h0[HSZ + off];
  const size_t xoff = (size_t)bid * 1024 + j * 64 + b;
  f16 xpre[4];
#pragma unroll
  for (int q = 0; q < 4; ++q) xpre[q] = xgP[xoff + q * 256];

  for (int k = 0; k <= NT; ++k) {
    // ---- two-level device barrier: release -> aggregate -> fence(inv)
    __syncthreads();                                  // drain block's stores
    if (tid == 0) {
      unsigned t16 = (unsigned)(k + 1) * 16u;
      __hip_atomic_fetch_add(&ctr[gid * 32], 1u, __ATOMIC_RELEASE, __HIP_MEMORY_SCOPE_AGENT);
      if (leader) {
        while (__hip_atomic_load(&ctr[gid * 32], __ATOMIC_RELAXED, __HIP_MEMORY_SCOPE_AGENT) < t16)
          __builtin_amdgcn_s_sleep(1);
        __threadfence();
        __hip_atomic_fetch_add(&ctr[1024], 1u, __ATOMIC_RELEASE, __HIP_MEMORY_SCOPE_AGENT);
      }
      while (__hip_atomic_load(&ctr[1024], __ATOMIC_RELAXED, __HIP_MEMORY_SCOPE_AGENT) < t16)
        __builtin_amdgcn_s_sleep(1);
      __threadfence();
    }
    __syncthreads();

    const bool do0 = (k < NT), do1 = (k >= 1);
    const f16* aprev = aping + ((k + 1) & 1) * HSZ;   // a[k-1]
    f16*       acur  = aping + (k & 1) * HSZ;         // a[k]
    const f16* zb    = (k <= 1) ? zinit : h2seq + (size_t)(k - 2) * HSZ;  // z[k-2]

    // ---- triple GEMM slice: acc0 = Whh0*a, acc1 = Whh1*z + Wih1*a
    f32x4 acc0[4] = {}, acc1[4] = {};
    half8 hA[2][4], hZ[2][4];
    {
      int kx = w * 256 + lg * 8;
#pragma unroll
      for (int nb = 0; nb < 4; ++nb) {
        size_t ro = (size_t)(nb * 16 + li) * DIMD + kx;
        hA[0][nb] = *(const half8*)(aprev + ro);
        hZ[0][nb] = *(const half8*)(zb + ro);
      }
    }
#pragma unroll
    for (int kk = 0; kk < 8; ++kk) {
      int cur = kk & 1, nxt = cur ^ 1;
      if (kk < 7) {
        int kx = w * 256 + (kk + 1) * 32 + lg * 8;
#pragma unroll
        for (int nb = 0; nb < 4; ++nb) {
          size_t ro = (size_t)(nb * 16 + li) * DIMD + kx;
          hA[nxt][nb] = *(const half8*)(aprev + ro);
          hZ[nxt][nb] = *(const half8*)(zb + ro);
        }
      }
#pragma unroll
      for (int nb = 0; nb < 4; ++nb) {
        acc0[nb] = __builtin_amdgcn_mfma_f32_16x16x32_f16(wf0[kk], hA[cur][nb], acc0[nb], 0, 0, 0);
        acc1[nb] = __builtin_amdgcn_mfma_f32_16x16x32_f16(wfZ[kk], hZ[cur][nb], acc1[nb], 0, 0, 0);
        acc1[nb] = __builtin_amdgcn_mfma_f32_16x16x32_f16(wfI[kk], hA[cur][nb], acc1[nb], 0, 0, 0);
      }
    }

    // ---- K-partials -> LDS (D row rr=lg*4+r, col b=nb*16+li)
#pragma unroll
    for (int nb = 0; nb < 4; ++nb) {
      *(f32x4*)&part[w][nb * 16 + li][lg * 4]      = acc0[nb];
      *(f32x4*)&part[w][nb * 16 + li][32 + lg * 4] = acc1[nb];
    }

    // prefetch next interval's xg chunk into registers (inv-immune)
    f16 xnxt[4] = {};
    if (k + 1 < NT) {
      const size_t xb = (size_t)(k + 1) * XGSTEP + xoff;
#pragma unroll
      for (int q = 0; q < 4; ++q) xnxt[q] = xgP[xb + q * 256];
    }
    __syncthreads();

    if (do0) {                                        // layer0 step k
      float g[4];
#pragma unroll
      for (int q = 0; q < 4; ++q) {
        int rr = q * 4 + j;
        g[q] = part[0][b][rr] + part[1][b][rr] + part[2][b][rr] + part[3][b][rr] + (float)xpre[q];
      }
      float cn = sigm(g[1]) * c0reg + sigm(g[0]) * tanh_(g[2]);
      float hn = sigm(g[3]) * tanh_(cn);
      c0reg = cn;
      acur[off] = (f16)hn;
      if (k == NT - 1) { hT[off] = hn; cT[off] = cn; }
    }
    if (do1) {                                        // layer1 step k-1
      float g[4];
#pragma unroll
      for (int q = 0; q < 4; ++q) {
        int rr = 32 + q * 4 + j;
        g[q] = part[0][b][rr] + part[1][b][rr] + part[2][b][rr] + part[3][b][rr] + bs1[q];
      }
      float cn = sigm(g[1]) * c1reg + sigm(g[0]) * tanh_(g[2]);
      float hn = sigm(g[3]) * tanh_(cn);
      c1reg = cn;
      h2seq[(size_t)(k - 1) * HSZ + off] = (f16)hn;
      if (k == NT) { hT[HSZ + off] = hn; cT[HSZ + off] = cn; }
    }
#pragma unroll
    for (int q = 0; q < 4; ++q) xpre[q] = xnxt[q];
  }
}

// =====================================================================
// Prep kernels
// =====================================================================
__global__ void wn_conv(const float* __restrict__ v, const float* __restrict__ gw,
                        f16* __restrict__ out, int K)
{
  int w = threadIdx.x >> 6, l = threadIdx.x & 63;
  int row = blockIdx.x * 4 + w;
  const float* vr = v + (size_t)row * K;
  float s = 0.f;
  for (int k = l; k < K; k += 64) { float x = vr[k]; s += x * x; }
#pragma unroll
  for (int off = 32; off > 0; off >>= 1) s += __shfl_xor(s, off, 64);
  float scale = gw[row] / sqrtf(s);
  f16* orow = out + (size_t)row * K;
  for (int k = l; k < K; k += 64) orow[k] = (f16)(vr[k] * scale);
}

__global__ void conv_f16(const float* __restrict__ src, f16* __restrict__ dst, int n4)
{
  int i = blockIdx.x * blockDim.x + threadIdx.x;
  if (i < n4) {
    float4 v = *(const float4*)(src + (size_t)i * 4);
    f16* d = dst + (size_t)i * 4;
    d[0] = (f16)v.x; d[1] = (f16)v.y; d[2] = (f16)v.z; d[3] = (f16)v.w;
  }
}

__global__ void bias_prep(const float* a0, const float* b0, const float* a1, const float* b1,
                          float* s0, float* s1, unsigned* ctr)
{
  int i = blockIdx.x * blockDim.x + threadIdx.x;
  if (i < G4) { s0[i] = a0[i] + b0[i]; s1[i] = a1[i] + b1[i]; }
  if (i < 2048) ctr[i] = 0;              // barrier counters (grp lines + root)
}

__global__ void embed_k(const int* __restrict__ x, const float* __restrict__ emb,
                        f16* __restrict__ e)
{
  int m = blockIdx.x;
  int k = threadIdx.x;
  e[(size_t)m * EMBD + k] = (f16)emb[(size_t)x[m] * EMBD + k];
}

// =====================================================================
extern "C" void kernel_launch(void* const* d_in, const int* in_sizes, int n_in,
                              void* d_out, int out_size, void* d_ws, size_t ws_size,
                              hipStream_t stream)
{
  (void)in_sizes; (void)n_in; (void)out_size; (void)ws_size;
  const int*   x     = (const int*)  d_in[0];
  const float* h0    = (const float*)d_in[1];
  const float* c0    = (const float*)d_in[2];
  const float* emb   = (const float*)d_in[3];
  const float* v_ih0 = (const float*)d_in[4];
  const float* g_ih0 = (const float*)d_in[5];
  const float* v_hh0 = (const float*)d_in[6];
  const float* g_hh0 = (const float*)d_in[7];
  const float* b_ih0 = (const float*)d_in[8];
  const float* b_hh0 = (const float*)d_in[9];
  const float* W_ih1 = (const float*)d_in[10];
  const float* W_hh1 = (const float*)d_in[11];
  const float* b_ih1 = (const float*)d_in[12];
  const float* b_hh1 = (const float*)d_in[13];
  const float* W_out = (const float*)d_in[14];
  const float* b_out = (const float*)d_in[15];

  char* ws = (char*)d_ws;
  size_t off = 0;
  auto alloc = [&](size_t bytes) { void* p = ws + off; off += (bytes + 255) & ~(size_t)255; return p; };
  f16*      Wih0h = (f16*)alloc((size_t)G4 * EMBD * 2);
  f16*      Whh0h = (f16*)alloc((size_t)G4 * DIMD * 2);
  f16*      Wih1h = (f16*)alloc((size_t)G4 * DIMD * 2);
  f16*      Whh1h = (f16*)alloc((size_t)G4 * DIMD * 2);
  f16*      Wouth = (f16*)alloc((size_t)256 * DIMD * 2);
  float*    bsum0 = (float*)alloc(G4 * 4);
  float*    bsum1 = (float*)alloc(G4 * 4);
  unsigned* ctr   = (unsigned*)alloc(2048 * 4);
  f16*      e_h   = (f16*)alloc((size_t)MTOT * EMBD * 2);
  f16*      xgP   = (f16*)alloc((size_t)NT * XGSTEP * 2);   // 128 MB packed
  f16*      h2s   = (f16*)alloc((size_t)NT * HSZ * 2);      // [t][b][d]
  f16*      aping = (f16*)alloc((size_t)2 * HSZ * 2);
  f16*      zinit = (f16*)alloc((size_t)HSZ * 2);
  // ~195 MB total

  float* logits = (float*)d_out;
  float* newh = logits + (size_t)MTOT * 256;
  float* newc = newh + 2 * HSZ;

  wn_conv<<<1024, 256, 0, stream>>>(v_ih0, g_ih0, Wih0h, EMBD);
  wn_conv<<<1024, 256, 0, stream>>>(v_hh0, g_hh0, Whh0h, DIMD);
  conv_f16<<<4096, 256, 0, stream>>>(W_ih1, Wih1h, 1048576);
  conv_f16<<<4096, 256, 0, stream>>>(W_hh1, Whh1h, 1048576);
  conv_f16<<<256, 256, 0, stream>>>(W_out, Wouth, 65536);
  bias_prep<<<16, 256, 0, stream>>>(b_ih0, b_hh0, b_ih1, b_hh1, bsum0, bsum1, ctr);
  embed_k<<<MTOT, 256, 0, stream>>>(x, emb, e_h);

  // xgP packed = W_ih0 * e^T (+ b_ih0 + b_hh0)
  gemm_bt<2><<<dim3(128, 32), 256, 0, stream>>>(e_h, Wih0h, xgP, bsum0, G4, EMBD);

  { // fused 2-layer recurrence
    const f16* xgc = xgP; const f16* W0 = Whh0h; const f16* W1 = Whh1h; const f16* WI = Wih1h;
    const float* bs = bsum1; const float* h0p = h0; const float* c0p = c0;
    f16* hs = h2s; f16* ap = aping; f16* zi = zinit;
    float* hTp = newh; float* cTp = newc; unsigned* ct = ctr;
    void* args[] = {&xgc, &W0, &W1, &WI, &bs, &h0p, &c0p, &hs, &ap, &zi, &hTp, &cTp, &ct};
    (void)hipLaunchCooperativeKernel((const void*)lstm_fused, dim3(NBLK), dim3(256), args, 0, stream);
  }

  // logits[b*NT+t][v] = h2s(t-major) * W_out^T + b_out
  gemm_bt<3><<<dim3(128, 2), 256, 0, stream>>>(h2s, Wouth, logits, b_out, 256, DIMD);
}